// Round 4
// baseline (467.779 us; speedup 1.0000x reference)
//
#include <hip/hip_runtime.h>
#include <hip/hip_bf16.h>

#define B_ROWS 16384
#define D_COLS 4096
#define BLOCK 256
#define WAVES_PER_BLOCK (BLOCK / 64)
// One wave per row: 4096 float/row = 1024 float4 / 64 lanes = 16 float4 per lane per input.
#define F4_PER_LANE (D_COLS / 4 / 64)
#define BATCH 8

typedef float f32x4 __attribute__((ext_vector_type(4)));

__global__ __launch_bounds__(BLOCK, 4) void cos_sim_kernel(
    const float* __restrict__ x1,
    const float* __restrict__ x2,
    float* __restrict__ out)
{
    const int wave = threadIdx.x >> 6;
    const int lane = threadIdx.x & 63;
    const int row  = blockIdx.x * WAVES_PER_BLOCK + wave;
    const size_t base = (size_t)row * D_COLS;

    const f32x4* __restrict__ r1 = reinterpret_cast<const f32x4*>(x1 + base);
    const f32x4* __restrict__ r2 = reinterpret_cast<const f32x4*>(x2 + base);

    float dot = 0.0f, sx = 0.0f, sy = 0.0f;

    // Batch loads: issue 16 x 16B nontemporal loads before any FMA so the
    // wave has deep memory-level parallelism at each waitcnt drain.
#pragma unroll
    for (int bat = 0; bat < F4_PER_LANE / BATCH; ++bat) {
        f32x4 a[BATCH], b[BATCH];
#pragma unroll
        for (int i = 0; i < BATCH; ++i) {
            const int j = lane + (bat * BATCH + i) * 64;
            a[i] = __builtin_nontemporal_load(&r1[j]);
            b[i] = __builtin_nontemporal_load(&r2[j]);
        }
#pragma unroll
        for (int i = 0; i < BATCH; ++i) {
            dot += a[i].x * b[i].x + a[i].y * b[i].y + a[i].z * b[i].z + a[i].w * b[i].w;
            sx  += a[i].x * a[i].x + a[i].y * a[i].y + a[i].z * a[i].z + a[i].w * a[i].w;
            sy  += b[i].x * b[i].x + b[i].y * b[i].y + b[i].z * b[i].z + b[i].w * b[i].w;
        }
    }

    // Wave-64 butterfly reduction — no LDS, no barrier.
#pragma unroll
    for (int off = 32; off > 0; off >>= 1) {
        dot += __shfl_down(dot, off, 64);
        sx  += __shfl_down(sx,  off, 64);
        sy  += __shfl_down(sy,  off, 64);
    }

    if (lane == 0) {
        out[row] = 0.5f * dot / (sqrtf(sx) * sqrtf(sy));
    }
}

extern "C" void kernel_launch(void* const* d_in, const int* in_sizes, int n_in,
                              void* d_out, int out_size, void* d_ws, size_t ws_size,
                              hipStream_t stream) {
    const float* x1 = (const float*)d_in[0];
    const float* x2 = (const float*)d_in[1];
    float* out = (float*)d_out;

    cos_sim_kernel<<<B_ROWS / WAVES_PER_BLOCK, BLOCK, 0, stream>>>(x1, x2, out);
}